// Round 11
// baseline (407.620 us; speedup 1.0000x reference)
//
#include <hip/hip_runtime.h>

typedef float f32x4 __attribute__((ext_vector_type(4)));
typedef short s16x8 __attribute__((ext_vector_type(8)));

// ---------- helpers ----------
__device__ __forceinline__ float us2f(unsigned short u) {
    union { unsigned int i; float f; } v;
    v.i = ((unsigned int)u) << 16;   // bf16 -> f32 exact
    return v.f;
}
__device__ __forceinline__ unsigned short f2us(float f) {
    union { unsigned int i; float f; } v; v.f = f;
    unsigned int r = v.i + 0x7fff + ((v.i >> 16) & 1);   // round-to-nearest-even
    return (unsigned short)(r >> 16);
}

// ================= W prep + bcnt zero =================
__global__ void k_wprep(const float* __restrict__ W1, const float* __restrict__ W2,
                        const float* __restrict__ W3, const float* __restrict__ Wc,
                        unsigned short* __restrict__ img, int* __restrict__ bcnt) {
    int b = blockIdx.x >> 7;         // layer 0..3, or 4 = bcnt-zero block
    int n = threadIdx.x;
    if (b >= 4) { bcnt[n] = 0; bcnt[n + 128] = 0; return; }
    int k = blockIdx.x & 127;        // k-row
    unsigned short *H, *L;
    float f;
    if (b < 3) {
        const float* W = (b == 0) ? W1 : ((b == 1) ? W2 : W3);
        H = img + b * 32768; L = H + 16384;
        f = W[k * 128 + n];
    } else {
        if (n >= 48) return;
        H = img + 3 * 32768; L = H + 6144;
        f = (n < 40) ? Wc[k * 40 + n] : 0.f;
    }
    unsigned short h = f2us(f);
    unsigned short l = f2us(f - us2f(h));
    int idx = n * 128 + ((((k >> 3) ^ (n & 15))) << 3) + (k & 7);
    H[idx] = h; L[idx] = l;
}

// ================= CSR build: two-level bucket sort =================
__global__ __launch_bounds__(256) void k_hist(const int* __restrict__ dst, int E, int chunk,
                                              int* __restrict__ bcnt) {
    __shared__ int cnt[256];
    int t = threadIdx.x;
    cnt[t] = 0; __syncthreads();
    int s = blockIdx.x * chunk;
    int e = s + chunk; if (e > E) e = E;
    for (int i = s + t; i < e; i += 256) atomicAdd(&cnt[dst[i] >> 8], 1);
    __syncthreads();
    if (cnt[t]) atomicAdd(&bcnt[t], cnt[t]);
}

__global__ void k_bscan(const int* __restrict__ bcnt, int* __restrict__ bofs,
                        int* __restrict__ gcur) {
    __shared__ int s[256];
    int t = threadIdx.x;
    int v = bcnt[t];
    s[t] = v; __syncthreads();
    for (int off = 1; off < 256; off <<= 1) {
        int x = (t >= off) ? s[t - off] : 0;
        __syncthreads();
        s[t] += x;
        __syncthreads();
    }
    int ex = s[t] - v;
    bofs[t] = ex; gcur[t] = ex;
    if (t == 255) bofs[256] = s[255];
}

__global__ __launch_bounds__(256) void k_scatter1(const int* __restrict__ src,
                                                  const int* __restrict__ dst, int E, int chunk,
                                                  int* __restrict__ gcur,
                                                  unsigned int* __restrict__ pk) {
    __shared__ int cnt[256];
    int t = threadIdx.x;
    cnt[t] = 0; __syncthreads();
    int s = blockIdx.x * chunk;
    int e = s + chunk; if (e > E) e = E;
    for (int i = s + t; i < e; i += 256) atomicAdd(&cnt[dst[i] >> 8], 1);
    __syncthreads();
    int base = atomicAdd(&gcur[t], cnt[t]);
    cnt[t] = base;
    __syncthreads();
    for (int i = s + t; i < e; i += 256) {
        int d = dst[i];
        int slot = atomicAdd(&cnt[d >> 8], 1);
        pk[slot] = ((unsigned int)src[i] << 8) | (unsigned int)(d & 255);
    }
}

__global__ __launch_bounds__(256) void k_degscan(const unsigned int* __restrict__ pk,
                                                 const int* __restrict__ bofs,
                                                 int* __restrict__ row_ptr,
                                                 int* __restrict__ bsum,
                                                 float* __restrict__ dinv, int N) {
    __shared__ int cnt[256];
    __shared__ int s[256];
    int t = threadIdx.x, b = blockIdx.x;
    cnt[t] = 0; __syncthreads();
    int s0 = bofs[b], s1 = bofs[b + 1];
    for (int i = s0 + t; i < s1; i += 256) atomicAdd(&cnt[pk[i] & 255], 1);
    __syncthreads();
    int v = cnt[t];
    s[t] = v; __syncthreads();
    for (int off = 1; off < 256; off <<= 1) {
        int x = (t >= off) ? s[t - off] : 0;
        __syncthreads();
        s[t] += x;
        __syncthreads();
    }
    int node = (b << 8) + t;
    if (node < N) {
        row_ptr[node] = s[t] - v;                 // exclusive within bucket
        dinv[node] = rsqrtf((float)(v + 1));      // +1 self-loop
    }
    if (t == 255) bsum[b] = s[255];
}

__global__ void k_scan2(int* __restrict__ bsum, int nb) {  // nb <= 256
    __shared__ int s[256];
    int t = threadIdx.x;
    int v = (t < nb) ? bsum[t] : 0;
    s[t] = v; __syncthreads();
    for (int off = 1; off < 256; off <<= 1) {
        int x = (t >= off) ? s[t - off] : 0;
        __syncthreads();
        s[t] += x;
        __syncthreads();
    }
    if (t < nb) bsum[t] = s[t] - v;
}

__global__ __launch_bounds__(256) void k_scatter2(const unsigned int* __restrict__ pk,
                                                  const int* __restrict__ bofs,
                                                  int* __restrict__ row_ptr,
                                                  const int* __restrict__ bsum,
                                                  int* __restrict__ csr, int N, int E) {
    __shared__ int cur[256];
    int t = threadIdx.x, b = blockIdx.x;
    int node = (b << 8) + t;
    int rp = 0;
    if (node < N) {
        rp = row_ptr[node] + bsum[b];
        row_ptr[node] = rp;                       // finalize for gather
    }
    cur[t] = rp;
    __syncthreads();
    int s = bofs[b], e = bofs[b + 1];
    for (int i = s + t; i < e; i += 256) {
        unsigned int v = pk[i];
        int slot = atomicAdd(&cur[v & 255], 1);
        csr[slot] = (int)(v >> 8);
    }
    if (node == N - 1) row_ptr[N] = E;
}

// ================= MFMA GEMM: M_q[q][i][c'] = bf16((A@W)[i][c] * dinv[i]) =============
// M stored QUARTER-MAJOR: quarter q = cols 32q..32q+31 (64 B bf16 rows) so each
// gather pass has a 3.2 MB working set (fits per-XCD L2).
// A fp32: hi/lo split, 3 MFMAs. A bf16: al==0 -> 2 MFMAs, half the A-bytes.
template <bool ABF16>
__global__ __launch_bounds__(256) void k_gemm128m(const void* __restrict__ Ap,
                                                  const unsigned short* __restrict__ img,
                                                  const float* __restrict__ dinv,
                                                  unsigned short* __restrict__ M, int N) {
    __shared__ __align__(16) unsigned short WsH[16384];   // 32 KB
    __shared__ __align__(16) unsigned short WsL[16384];   // 32 KB
    int t = threadIdx.x;
    {
        const uint4* s = (const uint4*)img;
        uint4* dH = (uint4*)WsH; uint4* dL = (uint4*)WsL;
#pragma unroll
        for (int i = 0; i < 8; i++) dH[t + i * 256] = s[t + i * 256];
#pragma unroll
        for (int i = 0; i < 8; i++) dL[t + i * 256] = s[2048 + t + i * 256];
    }
    __syncthreads();

    int w = t >> 6, lane = t & 63;
    int m = lane & 15, q = lane >> 4;
    int row0 = blockIdx.x * 64 + w * 16;
    int gr = row0 + m;
    int grc = (gr < N) ? gr : (N - 1);
    const float* A32 = (const float*)Ap + (size_t)grc * 128;
    const unsigned short* A16 = (const unsigned short*)Ap + (size_t)grc * 128;
    int nbase = m * 128;

    f32x4 acc[8];
#pragma unroll
    for (int cb = 0; cb < 8; cb++) { acc[cb][0]=0.f; acc[cb][1]=0.f; acc[cb][2]=0.f; acc[cb][3]=0.f; }

#pragma unroll
    for (int ks = 0; ks < 4; ks++) {
        union { unsigned short u[8]; s16x8 v; } ah, al;
        if constexpr (ABF16) {
            ah.v = *(const s16x8*)&A16[ks * 32 + q * 8];
        } else {
            float4 f0 = ((const float4*)A32)[ks * 8 + q * 2];
            float4 f1 = ((const float4*)A32)[ks * 8 + q * 2 + 1];
            float fv[8] = {f0.x, f0.y, f0.z, f0.w, f1.x, f1.y, f1.z, f1.w};
#pragma unroll
            for (int j = 0; j < 8; j++) {
                unsigned short h = f2us(fv[j]);
                ah.u[j] = h;
                al.u[j] = f2us(fv[j] - us2f(h));
            }
        }
        int koff = (((ks * 4 + q) ^ m) & 15) << 3;
#pragma unroll
        for (int cb = 0; cb < 8; cb++) {
            int o = cb * 2048 + nbase + koff;
            s16x8 wh = *(const s16x8*)&WsH[o];
            s16x8 wl = *(const s16x8*)&WsL[o];
            acc[cb] = __builtin_amdgcn_mfma_f32_16x16x32_bf16(ah.v, wh, acc[cb], 0, 0, 0);
            acc[cb] = __builtin_amdgcn_mfma_f32_16x16x32_bf16(ah.v, wl, acc[cb], 0, 0, 0);
            if constexpr (!ABF16)
                acc[cb] = __builtin_amdgcn_mfma_f32_16x16x32_bf16(al.v, wh, acc[cb], 0, 0, 0);
        }
    }

#pragma unroll
    for (int r = 0; r < 4; r++) {
        int grow = row0 + q * 4 + r;
        if (grow < N) {
            float dv = dinv[grow];
#pragma unroll
            for (int cb = 0; cb < 8; cb++) {
                // col = cb*16+m -> quarter cb>>1, within (cb&1)*16+m
                M[((size_t)(cb >> 1) * N + grow) * 32 + (cb & 1) * 16 + m] =
                    f2us(acc[cb][r] * dv);
            }
        }
    }
}

// ================= MFMA classifier: out = h3 @ Wc + bc (cols padded to 48) =========
__global__ __launch_bounds__(256) void k_gemm40m(const float* __restrict__ A,
                                                 const unsigned short* __restrict__ img,
                                                 const float* __restrict__ bc,
                                                 float* __restrict__ out, int N) {
    __shared__ __align__(16) unsigned short WsH[6144];    // 12 KB
    __shared__ __align__(16) unsigned short WsL[6144];    // 12 KB
    int t = threadIdx.x;
    {
        const uint4* s = (const uint4*)img;
        uint4* dH = (uint4*)WsH; uint4* dL = (uint4*)WsL;
#pragma unroll
        for (int i = 0; i < 3; i++) dH[t + i * 256] = s[t + i * 256];
#pragma unroll
        for (int i = 0; i < 3; i++) dL[t + i * 256] = s[768 + t + i * 256];
    }
    __syncthreads();

    int w = t >> 6, lane = t & 63;
    int m = lane & 15, q = lane >> 4;
    int row0 = blockIdx.x * 64 + w * 16;
    int gr = row0 + m;
    int grc = (gr < N) ? gr : (N - 1);
    const float4* Arow = (const float4*)(A + (size_t)grc * 128);
    int nbase = m * 128;

    f32x4 acc[3];
#pragma unroll
    for (int cb = 0; cb < 3; cb++) { acc[cb][0]=0.f; acc[cb][1]=0.f; acc[cb][2]=0.f; acc[cb][3]=0.f; }

#pragma unroll
    for (int ks = 0; ks < 4; ks++) {
        float4 f0 = Arow[ks * 8 + q * 2];
        float4 f1 = Arow[ks * 8 + q * 2 + 1];
        float fv[8] = {f0.x, f0.y, f0.z, f0.w, f1.x, f1.y, f1.z, f1.w};
        union { unsigned short u[8]; s16x8 v; } ah, al;
#pragma unroll
        for (int j = 0; j < 8; j++) {
            unsigned short h = f2us(fv[j]);
            ah.u[j] = h;
            al.u[j] = f2us(fv[j] - us2f(h));
        }
        int koff = (((ks * 4 + q) ^ m) & 15) << 3;
#pragma unroll
        for (int cb = 0; cb < 3; cb++) {
            int o = cb * 2048 + nbase + koff;
            s16x8 wh = *(const s16x8*)&WsH[o];
            s16x8 wl = *(const s16x8*)&WsL[o];
            acc[cb] = __builtin_amdgcn_mfma_f32_16x16x32_bf16(ah.v, wh, acc[cb], 0, 0, 0);
            acc[cb] = __builtin_amdgcn_mfma_f32_16x16x32_bf16(ah.v, wl, acc[cb], 0, 0, 0);
            acc[cb] = __builtin_amdgcn_mfma_f32_16x16x32_bf16(al.v, wh, acc[cb], 0, 0, 0);
        }
    }

#pragma unroll
    for (int r = 0; r < 4; r++) {
        int grow = row0 + q * 4 + r;
        if (grow < N) {
#pragma unroll
            for (int cb = 0; cb < 3; cb++) {
                int col = cb * 16 + m;
                if (col < 40) out[(size_t)grow * 40 + col] = acc[cb][r] + bc[col];
            }
        }
    }
}

// ---------- gather v3: feature-quarter passes, L2-resident M_q ----------
// blockIdx.y = quarter (dispatch-order phasing heuristic). Per pass each wave
// handles one node; 4 lane-groups of 16 fetch 4 neighbor quarter-rows (64 B =
// exactly one cache line each). M_q = 3.2 MB fits per-XCD L2; H written with
// nontemporal stores so the stream doesn't evict M_q. All __shfl broadcasts
// full-wave (bpermute from inactive lane is undefined); accum predicated.
template <bool OUT_BF16>
__global__ __launch_bounds__(256) void k_gather(const unsigned short* __restrict__ M,
                                                const int* __restrict__ csr,
                                                const int* __restrict__ row_ptr,
                                                const float* __restrict__ dinv,
                                                const float* __restrict__ bias,
                                                void* __restrict__ H, int N) {
    int qtr  = blockIdx.y;                       // feature quarter 0..3
    int w    = (blockIdx.x << 2) + (threadIdx.x >> 6);
    int lane = threadIdx.x & 63;
    if (w >= N) return;
    int g  = lane >> 4;      // neighbor group 0..3
    int sl = lane & 15;      // uint slot within quarter-row (16 x 4 B = 64 B)

    const unsigned int* Mq = (const unsigned int*)M + (size_t)qtr * N * 16;
    float ax = 0.f, ay = 0.f;
    auto accum = [&](unsigned int v) {
        ax += us2f((unsigned short)(v & 0xffffu));
        ay += us2f((unsigned short)(v >> 16));
    };

    if (g == 0) accum(Mq[(size_t)w * 16 + sl]);  // self term (once)

    int s0 = row_ptr[w], s1 = row_ptr[w + 1];
    for (int base = s0; base < s1; base += 64) {
        int n = s1 - base; if (n > 64) n = 64;
        int idx = (lane < n) ? csr[base + lane] : 0;
        int full = n >> 2;
        int rem  = n & 3;
        int j = 0;
        for (; j + 4 <= full; j += 4) {
            int u0 = __shfl(idx, (j + 0) * 4 + g);
            int u1 = __shfl(idx, (j + 1) * 4 + g);
            int u2 = __shfl(idx, (j + 2) * 4 + g);
            int u3 = __shfl(idx, (j + 3) * 4 + g);
            unsigned int t0 = Mq[(size_t)u0 * 16 + sl];
            unsigned int t1 = Mq[(size_t)u1 * 16 + sl];
            unsigned int t2 = Mq[(size_t)u2 * 16 + sl];
            unsigned int t3 = Mq[(size_t)u3 * 16 + sl];
            accum(t0); accum(t1); accum(t2); accum(t3);
        }
        for (; j < full; j++) {
            int u = __shfl(idx, j * 4 + g);
            accum(Mq[(size_t)u * 16 + sl]);
        }
        int ur = __shfl(idx, ((full << 2) + g) & 63);   // full-wave (r9 lesson)
        if (g < rem) accum(Mq[(size_t)ur * 16 + sl]);
    }

    // reduce across the 4 groups
    ax += __shfl_xor(ax, 16); ax += __shfl_xor(ax, 32);
    ay += __shfl_xor(ay, 16); ay += __shfl_xor(ay, 32);

    if (g == 0) {
        float dv = dinv[w];
        int f0 = qtr * 32 + sl * 2;
        float ox = fmaxf(fmaf(dv, ax, bias[f0]), 0.f);
        float oy = fmaxf(fmaf(dv, ay, bias[f0 + 1]), 0.f);
        if constexpr (OUT_BF16) {
            unsigned int pkd = (unsigned int)f2us(ox) | ((unsigned int)f2us(oy) << 16);
            __builtin_nontemporal_store(pkd,
                (unsigned int*)H + (size_t)w * 64 + qtr * 16 + sl);
        } else {
            float* Hp = (float*)H + (size_t)w * 128 + f0;
            Hp[0] = ox; Hp[1] = oy;
        }
    }
}

// ---------- launch ----------
extern "C" void kernel_launch(void* const* d_in, const int* in_sizes, int n_in,
                              void* d_out, int out_size, void* d_ws, size_t ws_size,
                              hipStream_t stream) {
    const float* x  = (const float*)d_in[0];
    const int*   ei = (const int*)d_in[1];
    const float* W1 = (const float*)d_in[2];
    const float* b1 = (const float*)d_in[3];
    const float* W2 = (const float*)d_in[4];
    const float* b2 = (const float*)d_in[5];
    const float* W3 = (const float*)d_in[6];
    const float* b3 = (const float*)d_in[7];
    const float* Wc = (const float*)d_in[8];
    const float* bc = (const float*)d_in[9];

    const int N = in_sizes[0] / 128;   // 50000
    const int E = in_sizes[1] / 2;     // 800000
    const int* src = ei;
    const int* dst = ei + E;

    // workspace carve-out (~33 MB)
    char* ws = (char*)d_ws;
    size_t off = 0;
    auto alloc = [&](size_t bytes) -> void* {
        void* p = ws + off;
        off = (off + bytes + 255) & ~(size_t)255;
        return p;
    };
    unsigned short* Mbuf = (unsigned short*)alloc((size_t)N * 128 * 2);  // bf16, quarter-major
    unsigned short* Hb   = (unsigned short*)alloc((size_t)N * 128 * 2);  // bf16 H (layers 1,2)
    unsigned int* pk     = (unsigned int*)alloc((size_t)E * 4);          // bucketed edges
    unsigned short* img  = (unsigned short*)alloc((3 * 32768 + 2 * 6144) * 2);
    float* dinv    = (float*)alloc((size_t)N * 4);
    int*   row_ptr = (int*)alloc((size_t)(N + 1) * 4);
    int*   csr     = (int*)alloc((size_t)E * 4);
    int*   bcnt    = (int*)alloc(256 * 4);
    int*   bofs    = (int*)alloc(257 * 4);
    int*   gcur    = (int*)alloc(256 * 4);
    int*   bsum    = (int*)alloc(256 * 4);

    float* out  = (float*)d_out;               // logits [N,40]
    float* hbuf = out + (size_t)N * 40;        // h3 region [N,128] fp32 (output)

    const int nb  = (N + 255) / 256;   // 196 (<=256, required by k_scan2)
    const int NB  = (N + 255) >> 8;    // node buckets (196)
    const int G1  = 256;
    const int chunk = (E + G1 - 1) / G1;

    // weight prep (bf16 hi/lo swizzled images) + bcnt zero (block 512)
    k_wprep<<<513, 128, 0, stream>>>(W1, W2, W3, Wc, img, bcnt);

    // CSR build: bucket sort (dst>>8) -> per-bucket degree+scan -> placement
    k_hist<<<G1, 256, 0, stream>>>(dst, E, chunk, bcnt);
    k_bscan<<<1, 256, 0, stream>>>(bcnt, bofs, gcur);
    k_scatter1<<<G1, 256, 0, stream>>>(src, dst, E, chunk, gcur, pk);
    k_degscan<<<NB, 256, 0, stream>>>(pk, bofs, row_ptr, bsum, dinv, N);
    k_scan2<<<1, 256, 0, stream>>>(bsum, nb);
    k_scatter2<<<NB, 256, 0, stream>>>(pk, bofs, row_ptr, bsum, csr, N, E);

    const int gb  = (N + 63) / 64;           // gemm blocks (BM=64)
    const dim3 gg((N + 3) / 4, 4, 1);        // gather: x = node blocks, y = quarter

    // layer 1: x(fp32) -> M_q -> Hb(bf16)
    k_gemm128m<false><<<gb, 256, 0, stream>>>(x, img, dinv, Mbuf, N);
    k_gather<true><<<gg, 256, 0, stream>>>(Mbuf, csr, row_ptr, dinv, b1, Hb, N);
    // layer 2: Hb(bf16) -> M_q -> Hb
    k_gemm128m<true><<<gb, 256, 0, stream>>>(Hb, img + 32768, dinv, Mbuf, N);
    k_gather<true><<<gg, 256, 0, stream>>>(Mbuf, csr, row_ptr, dinv, b2, Hb, N);
    // layer 3: Hb(bf16) -> M_q -> h3(fp32, d_out)
    k_gemm128m<true><<<gb, 256, 0, stream>>>(Hb, img + 2 * 32768, dinv, Mbuf, N);
    k_gather<false><<<gg, 256, 0, stream>>>(Mbuf, csr, row_ptr, dinv, b3, hbuf, N);
    // classifier reads h3 fp32
    k_gemm40m<<<gb, 256, 0, stream>>>(hbuf, img + 3 * 32768, bc, out, N);
}

// Round 12
// 282.827 us; speedup vs baseline: 1.4412x; 1.4412x over previous
//
#include <hip/hip_runtime.h>

typedef float f32x4 __attribute__((ext_vector_type(4)));
typedef short s16x8 __attribute__((ext_vector_type(8)));

// ---------- helpers ----------
__device__ __forceinline__ float us2f(unsigned short u) {
    union { unsigned int i; float f; } v;
    v.i = ((unsigned int)u) << 16;   // bf16 -> f32 exact
    return v.f;
}
__device__ __forceinline__ unsigned short f2us(float f) {
    union { unsigned int i; float f; } v; v.f = f;
    unsigned int r = v.i + 0x7fff + ((v.i >> 16) & 1);   // round-to-nearest-even
    return (unsigned short)(r >> 16);
}

// ================= W prep + bcnt zero =================
__global__ void k_wprep(const float* __restrict__ W1, const float* __restrict__ W2,
                        const float* __restrict__ W3, const float* __restrict__ Wc,
                        unsigned short* __restrict__ img, int* __restrict__ bcnt) {
    int b = blockIdx.x >> 7;         // layer 0..3, or 4 = bcnt-zero block
    int n = threadIdx.x;
    if (b >= 4) { bcnt[n] = 0; bcnt[n + 128] = 0; return; }
    int k = blockIdx.x & 127;        // k-row
    unsigned short *H, *L;
    float f;
    if (b < 3) {
        const float* W = (b == 0) ? W1 : ((b == 1) ? W2 : W3);
        H = img + b * 32768; L = H + 16384;
        f = W[k * 128 + n];
    } else {
        if (n >= 48) return;
        H = img + 3 * 32768; L = H + 6144;
        f = (n < 40) ? Wc[k * 40 + n] : 0.f;
    }
    unsigned short h = f2us(f);
    unsigned short l = f2us(f - us2f(h));
    int idx = n * 128 + ((((k >> 3) ^ (n & 15))) << 3) + (k & 7);
    H[idx] = h; L[idx] = l;
}

// ================= CSR build: two-level bucket sort =================
__global__ __launch_bounds__(256) void k_hist(const int* __restrict__ dst, int E, int chunk,
                                              int* __restrict__ bcnt) {
    __shared__ int cnt[256];
    int t = threadIdx.x;
    cnt[t] = 0; __syncthreads();
    int s = blockIdx.x * chunk;
    int e = s + chunk; if (e > E) e = E;
    for (int i = s + t; i < e; i += 256) atomicAdd(&cnt[dst[i] >> 8], 1);
    __syncthreads();
    if (cnt[t]) atomicAdd(&bcnt[t], cnt[t]);
}

__global__ void k_bscan(const int* __restrict__ bcnt, int* __restrict__ bofs,
                        int* __restrict__ gcur) {
    __shared__ int s[256];
    int t = threadIdx.x;
    int v = bcnt[t];
    s[t] = v; __syncthreads();
    for (int off = 1; off < 256; off <<= 1) {
        int x = (t >= off) ? s[t - off] : 0;
        __syncthreads();
        s[t] += x;
        __syncthreads();
    }
    int ex = s[t] - v;
    bofs[t] = ex; gcur[t] = ex;
    if (t == 255) bofs[256] = s[255];
}

__global__ __launch_bounds__(256) void k_scatter1(const int* __restrict__ src,
                                                  const int* __restrict__ dst, int E, int chunk,
                                                  int* __restrict__ gcur,
                                                  unsigned int* __restrict__ pk) {
    __shared__ int cnt[256];
    int t = threadIdx.x;
    cnt[t] = 0; __syncthreads();
    int s = blockIdx.x * chunk;
    int e = s + chunk; if (e > E) e = E;
    for (int i = s + t; i < e; i += 256) atomicAdd(&cnt[dst[i] >> 8], 1);
    __syncthreads();
    int base = atomicAdd(&gcur[t], cnt[t]);
    cnt[t] = base;
    __syncthreads();
    for (int i = s + t; i < e; i += 256) {
        int d = dst[i];
        int slot = atomicAdd(&cnt[d >> 8], 1);
        pk[slot] = ((unsigned int)src[i] << 8) | (unsigned int)(d & 255);
    }
}

__global__ __launch_bounds__(256) void k_degscan(const unsigned int* __restrict__ pk,
                                                 const int* __restrict__ bofs,
                                                 int* __restrict__ row_ptr,
                                                 int* __restrict__ bsum,
                                                 float* __restrict__ dinv, int N) {
    __shared__ int cnt[256];
    __shared__ int s[256];
    int t = threadIdx.x, b = blockIdx.x;
    cnt[t] = 0; __syncthreads();
    int s0 = bofs[b], s1 = bofs[b + 1];
    for (int i = s0 + t; i < s1; i += 256) atomicAdd(&cnt[pk[i] & 255], 1);
    __syncthreads();
    int v = cnt[t];
    s[t] = v; __syncthreads();
    for (int off = 1; off < 256; off <<= 1) {
        int x = (t >= off) ? s[t - off] : 0;
        __syncthreads();
        s[t] += x;
        __syncthreads();
    }
    int node = (b << 8) + t;
    if (node < N) {
        row_ptr[node] = s[t] - v;                 // exclusive within bucket
        dinv[node] = rsqrtf((float)(v + 1));      // +1 self-loop
    }
    if (t == 255) bsum[b] = s[255];
}

__global__ void k_scan2(int* __restrict__ bsum, int nb) {  // nb <= 256
    __shared__ int s[256];
    int t = threadIdx.x;
    int v = (t < nb) ? bsum[t] : 0;
    s[t] = v; __syncthreads();
    for (int off = 1; off < 256; off <<= 1) {
        int x = (t >= off) ? s[t - off] : 0;
        __syncthreads();
        s[t] += x;
        __syncthreads();
    }
    if (t < nb) bsum[t] = s[t] - v;
}

__global__ __launch_bounds__(256) void k_scatter2(const unsigned int* __restrict__ pk,
                                                  const int* __restrict__ bofs,
                                                  int* __restrict__ row_ptr,
                                                  const int* __restrict__ bsum,
                                                  int* __restrict__ csr, int N, int E) {
    __shared__ int cur[256];
    int t = threadIdx.x, b = blockIdx.x;
    int node = (b << 8) + t;
    int rp = 0;
    if (node < N) {
        rp = row_ptr[node] + bsum[b];
        row_ptr[node] = rp;                       // finalize for gather
    }
    cur[t] = rp;
    __syncthreads();
    int s = bofs[b], e = bofs[b + 1];
    for (int i = s + t; i < e; i += 256) {
        unsigned int v = pk[i];
        int slot = atomicAdd(&cur[v & 255], 1);
        csr[slot] = (int)(v >> 8);
    }
    if (node == N - 1) row_ptr[N] = E;
}

// ================= MFMA GEMM: M[i][c] = bf16((A@W)[i][c] * dinv[i]) =================
// Row-major M (256 B rows — the gather's unit). A fp32: hi/lo split, 3 MFMAs.
// A bf16 (Hb): al==0 -> 2 MFMAs, half the A-bytes.
template <bool ABF16>
__global__ __launch_bounds__(256) void k_gemm128m(const void* __restrict__ Ap,
                                                  const unsigned short* __restrict__ img,
                                                  const float* __restrict__ dinv,
                                                  unsigned short* __restrict__ M, int N) {
    __shared__ __align__(16) unsigned short WsH[16384];   // 32 KB
    __shared__ __align__(16) unsigned short WsL[16384];   // 32 KB
    int t = threadIdx.x;
    {
        const uint4* s = (const uint4*)img;
        uint4* dH = (uint4*)WsH; uint4* dL = (uint4*)WsL;
#pragma unroll
        for (int i = 0; i < 8; i++) dH[t + i * 256] = s[t + i * 256];
#pragma unroll
        for (int i = 0; i < 8; i++) dL[t + i * 256] = s[2048 + t + i * 256];
    }
    __syncthreads();

    int w = t >> 6, lane = t & 63;
    int m = lane & 15, q = lane >> 4;
    int row0 = blockIdx.x * 64 + w * 16;
    int gr = row0 + m;
    int grc = (gr < N) ? gr : (N - 1);
    const float* A32 = (const float*)Ap + (size_t)grc * 128;
    const unsigned short* A16 = (const unsigned short*)Ap + (size_t)grc * 128;
    int nbase = m * 128;

    f32x4 acc[8];
#pragma unroll
    for (int cb = 0; cb < 8; cb++) { acc[cb][0]=0.f; acc[cb][1]=0.f; acc[cb][2]=0.f; acc[cb][3]=0.f; }

#pragma unroll
    for (int ks = 0; ks < 4; ks++) {
        union { unsigned short u[8]; s16x8 v; } ah, al;
        if constexpr (ABF16) {
            ah.v = *(const s16x8*)&A16[ks * 32 + q * 8];
        } else {
            float4 f0 = ((const float4*)A32)[ks * 8 + q * 2];
            float4 f1 = ((const float4*)A32)[ks * 8 + q * 2 + 1];
            float fv[8] = {f0.x, f0.y, f0.z, f0.w, f1.x, f1.y, f1.z, f1.w};
#pragma unroll
            for (int j = 0; j < 8; j++) {
                unsigned short h = f2us(fv[j]);
                ah.u[j] = h;
                al.u[j] = f2us(fv[j] - us2f(h));
            }
        }
        int koff = (((ks * 4 + q) ^ m) & 15) << 3;
#pragma unroll
        for (int cb = 0; cb < 8; cb++) {
            int o = cb * 2048 + nbase + koff;
            s16x8 wh = *(const s16x8*)&WsH[o];
            s16x8 wl = *(const s16x8*)&WsL[o];
            acc[cb] = __builtin_amdgcn_mfma_f32_16x16x32_bf16(ah.v, wh, acc[cb], 0, 0, 0);
            acc[cb] = __builtin_amdgcn_mfma_f32_16x16x32_bf16(ah.v, wl, acc[cb], 0, 0, 0);
            if constexpr (!ABF16)
                acc[cb] = __builtin_amdgcn_mfma_f32_16x16x32_bf16(al.v, wh, acc[cb], 0, 0, 0);
        }
    }

#pragma unroll
    for (int r = 0; r < 4; r++) {
        int grow = row0 + q * 4 + r;
        if (grow < N) {
            float dv = dinv[grow];
#pragma unroll
            for (int cb = 0; cb < 8; cb++)
                M[(size_t)grow * 128 + cb * 16 + m] = f2us(acc[cb][r] * dv);
        }
    }
}

// ================= MFMA classifier: out = h3 @ Wc + bc (cols padded to 48) =========
__global__ __launch_bounds__(256) void k_gemm40m(const float* __restrict__ A,
                                                 const unsigned short* __restrict__ img,
                                                 const float* __restrict__ bc,
                                                 float* __restrict__ out, int N) {
    __shared__ __align__(16) unsigned short WsH[6144];    // 12 KB
    __shared__ __align__(16) unsigned short WsL[6144];    // 12 KB
    int t = threadIdx.x;
    {
        const uint4* s = (const uint4*)img;
        uint4* dH = (uint4*)WsH; uint4* dL = (uint4*)WsL;
#pragma unroll
        for (int i = 0; i < 3; i++) dH[t + i * 256] = s[t + i * 256];
#pragma unroll
        for (int i = 0; i < 3; i++) dL[t + i * 256] = s[768 + t + i * 256];
    }
    __syncthreads();

    int w = t >> 6, lane = t & 63;
    int m = lane & 15, q = lane >> 4;
    int row0 = blockIdx.x * 64 + w * 16;
    int gr = row0 + m;
    int grc = (gr < N) ? gr : (N - 1);
    const float4* Arow = (const float4*)(A + (size_t)grc * 128);
    int nbase = m * 128;

    f32x4 acc[3];
#pragma unroll
    for (int cb = 0; cb < 3; cb++) { acc[cb][0]=0.f; acc[cb][1]=0.f; acc[cb][2]=0.f; acc[cb][3]=0.f; }

#pragma unroll
    for (int ks = 0; ks < 4; ks++) {
        float4 f0 = Arow[ks * 8 + q * 2];
        float4 f1 = Arow[ks * 8 + q * 2 + 1];
        float fv[8] = {f0.x, f0.y, f0.z, f0.w, f1.x, f1.y, f1.z, f1.w};
        union { unsigned short u[8]; s16x8 v; } ah, al;
#pragma unroll
        for (int j = 0; j < 8; j++) {
            unsigned short h = f2us(fv[j]);
            ah.u[j] = h;
            al.u[j] = f2us(fv[j] - us2f(h));
        }
        int koff = (((ks * 4 + q) ^ m) & 15) << 3;
#pragma unroll
        for (int cb = 0; cb < 3; cb++) {
            int o = cb * 2048 + nbase + koff;
            s16x8 wh = *(const s16x8*)&WsH[o];
            s16x8 wl = *(const s16x8*)&WsL[o];
            acc[cb] = __builtin_amdgcn_mfma_f32_16x16x32_bf16(ah.v, wh, acc[cb], 0, 0, 0);
            acc[cb] = __builtin_amdgcn_mfma_f32_16x16x32_bf16(ah.v, wl, acc[cb], 0, 0, 0);
            acc[cb] = __builtin_amdgcn_mfma_f32_16x16x32_bf16(al.v, wh, acc[cb], 0, 0, 0);
        }
    }

#pragma unroll
    for (int r = 0; r < 4; r++) {
        int grow = row0 + q * 4 + r;
        if (grow < N) {
#pragma unroll
            for (int cb = 0; cb < 3; cb++) {
                int col = cb * 16 + m;
                if (col < 40) out[(size_t)grow * 40 + col] = acc[cb][r] + bc[col];
            }
        }
    }
}

// ---------- gather v2 (round-10 form): full 256 B rows, 4 rows/wave-instr ----------
// one wave per node; 4 lane-groups of 16; all __shfl broadcasts full-wave
// (bpermute from inactive lane undefined — r9 lesson); accum predicated.
// OUT_BF16: g==0 lanes pack 8 feats into one uint4 store (H bf16, layers 1-2).
template <bool OUT_BF16>
__global__ __launch_bounds__(256) void k_gather(const unsigned short* __restrict__ M,
                                                const int* __restrict__ csr,
                                                const int* __restrict__ row_ptr,
                                                const float* __restrict__ dinv,
                                                const float* __restrict__ bias,
                                                void* __restrict__ H, int N) {
    int w    = (blockIdx.x << 2) + (threadIdx.x >> 6);
    int lane = threadIdx.x & 63;
    if (w >= N) return;
    int g  = lane >> 4;      // neighbor group 0..3
    int sl = lane & 15;      // 16 B slot within row

    const uint4* M16 = (const uint4*)M;    // row = 16 uint4 (256 B)
    float acc[8];
#pragma unroll
    for (int i = 0; i < 8; i++) acc[i] = 0.f;

    auto accum = [&](uint4 tv) {
        unsigned int uu[4] = {tv.x, tv.y, tv.z, tv.w};
#pragma unroll
        for (int i = 0; i < 4; i++) {
            acc[2 * i]     += us2f((unsigned short)(uu[i] & 0xffffu));
            acc[2 * i + 1] += us2f((unsigned short)(uu[i] >> 16));
        }
    };

    if (g == 0) accum(M16[(size_t)w * 16 + sl]);   // self term (once)

    int s0 = row_ptr[w], s1 = row_ptr[w + 1];
    for (int base = s0; base < s1; base += 64) {
        int n = s1 - base; if (n > 64) n = 64;
        int idx = (lane < n) ? csr[base + lane] : 0;
        int full = n >> 2;
        int rem  = n & 3;
        int j = 0;
        for (; j + 4 <= full; j += 4) {            // full-wave shfls
            int u0 = __shfl(idx, (j + 0) * 4 + g);
            int u1 = __shfl(idx, (j + 1) * 4 + g);
            int u2 = __shfl(idx, (j + 2) * 4 + g);
            int u3 = __shfl(idx, (j + 3) * 4 + g);
            uint4 t0 = M16[(size_t)u0 * 16 + sl];
            uint4 t1 = M16[(size_t)u1 * 16 + sl];
            uint4 t2 = M16[(size_t)u2 * 16 + sl];
            uint4 t3 = M16[(size_t)u3 * 16 + sl];
            accum(t0); accum(t1); accum(t2); accum(t3);
        }
        for (; j < full; j++) {
            int u = __shfl(idx, j * 4 + g);
            accum(M16[(size_t)u * 16 + sl]);
        }
        int ur = __shfl(idx, ((full << 2) + g) & 63);   // full-wave
        if (g < rem) accum(M16[(size_t)ur * 16 + sl]);
    }

    // reduce across the 4 groups
#pragma unroll
    for (int i = 0; i < 8; i++) {
        acc[i] += __shfl_xor(acc[i], 16);
        acc[i] += __shfl_xor(acc[i], 32);
    }

    float dv = dinv[w];
    const float4* b4 = (const float4*)bias;
    float4 b0 = b4[sl * 2], b1 = b4[sl * 2 + 1];
    float o[8];
    o[0] = fmaxf(fmaf(dv, acc[0], b0.x), 0.f);
    o[1] = fmaxf(fmaf(dv, acc[1], b0.y), 0.f);
    o[2] = fmaxf(fmaf(dv, acc[2], b0.z), 0.f);
    o[3] = fmaxf(fmaf(dv, acc[3], b0.w), 0.f);
    o[4] = fmaxf(fmaf(dv, acc[4], b1.x), 0.f);
    o[5] = fmaxf(fmaf(dv, acc[5], b1.y), 0.f);
    o[6] = fmaxf(fmaf(dv, acc[6], b1.z), 0.f);
    o[7] = fmaxf(fmaf(dv, acc[7], b1.w), 0.f);

    if (g == 0) {
        if constexpr (OUT_BF16) {
            uint4 p;
            p.x = (unsigned int)f2us(o[0]) | ((unsigned int)f2us(o[1]) << 16);
            p.y = (unsigned int)f2us(o[2]) | ((unsigned int)f2us(o[3]) << 16);
            p.z = (unsigned int)f2us(o[4]) | ((unsigned int)f2us(o[5]) << 16);
            p.w = (unsigned int)f2us(o[6]) | ((unsigned int)f2us(o[7]) << 16);
            ((uint4*)H)[(size_t)w * 16 + sl] = p;
        } else {
            float4* H4 = (float4*)H;
            H4[(size_t)w * 32 + sl * 2]     = make_float4(o[0], o[1], o[2], o[3]);
            H4[(size_t)w * 32 + sl * 2 + 1] = make_float4(o[4], o[5], o[6], o[7]);
        }
    }
}

// ---------- launch ----------
extern "C" void kernel_launch(void* const* d_in, const int* in_sizes, int n_in,
                              void* d_out, int out_size, void* d_ws, size_t ws_size,
                              hipStream_t stream) {
    const float* x  = (const float*)d_in[0];
    const int*   ei = (const int*)d_in[1];
    const float* W1 = (const float*)d_in[2];
    const float* b1 = (const float*)d_in[3];
    const float* W2 = (const float*)d_in[4];
    const float* b2 = (const float*)d_in[5];
    const float* W3 = (const float*)d_in[6];
    const float* b3 = (const float*)d_in[7];
    const float* Wc = (const float*)d_in[8];
    const float* bc = (const float*)d_in[9];

    const int N = in_sizes[0] / 128;   // 50000
    const int E = in_sizes[1] / 2;     // 800000
    const int* src = ei;
    const int* dst = ei + E;

    // workspace carve-out (~33 MB)
    char* ws = (char*)d_ws;
    size_t off = 0;
    auto alloc = [&](size_t bytes) -> void* {
        void* p = ws + off;
        off = (off + bytes + 255) & ~(size_t)255;
        return p;
    };
    unsigned short* Mbuf = (unsigned short*)alloc((size_t)N * 128 * 2);  // bf16, row-major
    unsigned short* Hb   = (unsigned short*)alloc((size_t)N * 128 * 2);  // bf16 H (layers 1,2)
    unsigned int* pk     = (unsigned int*)alloc((size_t)E * 4);          // bucketed edges
    unsigned short* img  = (unsigned short*)alloc((3 * 32768 + 2 * 6144) * 2);
    float* dinv    = (float*)alloc((size_t)N * 4);
    int*   row_ptr = (int*)alloc((size_t)(N + 1) * 4);
    int*   csr     = (int*)alloc((size_t)E * 4);
    int*   bcnt    = (int*)alloc(256 * 4);
    int*   bofs    = (int*)alloc(257 * 4);
    int*   gcur    = (int*)alloc(256 * 4);
    int*   bsum    = (int*)alloc(256 * 4);

    float* out  = (float*)d_out;               // logits [N,40]
    float* hbuf = out + (size_t)N * 40;        // h3 region [N,128] fp32 (output)

    const int nb  = (N + 255) / 256;   // 196 (<=256, required by k_scan2)
    const int NB  = (N + 255) >> 8;    // node buckets (196)
    const int G1  = 256;
    const int chunk = (E + G1 - 1) / G1;

    // weight prep (bf16 hi/lo swizzled images) + bcnt zero (block 512)
    k_wprep<<<513, 128, 0, stream>>>(W1, W2, W3, Wc, img, bcnt);

    // CSR build: bucket sort (dst>>8) -> per-bucket degree+scan -> placement
    k_hist<<<G1, 256, 0, stream>>>(dst, E, chunk, bcnt);
    k_bscan<<<1, 256, 0, stream>>>(bcnt, bofs, gcur);
    k_scatter1<<<G1, 256, 0, stream>>>(src, dst, E, chunk, gcur, pk);
    k_degscan<<<NB, 256, 0, stream>>>(pk, bofs, row_ptr, bsum, dinv, N);
    k_scan2<<<1, 256, 0, stream>>>(bsum, nb);
    k_scatter2<<<NB, 256, 0, stream>>>(pk, bofs, row_ptr, bsum, csr, N, E);

    const int gb  = (N + 63) / 64;    // gemm blocks (BM=64)
    const int gab = (N + 3) / 4;      // gather blocks (4 waves/block)

    // layer 1: x(fp32) -> M -> Hb(bf16)
    k_gemm128m<false><<<gb, 256, 0, stream>>>(x, img, dinv, Mbuf, N);
    k_gather<true><<<gab, 256, 0, stream>>>(Mbuf, csr, row_ptr, dinv, b1, Hb, N);
    // layer 2: Hb(bf16) -> M -> Hb
    k_gemm128m<true><<<gb, 256, 0, stream>>>(Hb, img + 32768, dinv, Mbuf, N);
    k_gather<true><<<gab, 256, 0, stream>>>(Mbuf, csr, row_ptr, dinv, b2, Hb, N);
    // layer 3: Hb(bf16) -> M -> h3(fp32, d_out)
    k_gemm128m<true><<<gb, 256, 0, stream>>>(Hb, img + 2 * 32768, dinv, Mbuf, N);
    k_gather<false><<<gab, 256, 0, stream>>>(Mbuf, csr, row_ptr, dinv, b3, hbuf, N);
    // classifier reads h3 fp32
    k_gemm40m<<<gb, 256, 0, stream>>>(hbuf, img + 3 * 32768, bc, out, N);
}